// Round 2
// baseline (588.526 us; speedup 1.0000x reference)
//
#include <hip/hip_runtime.h>

#define DI __device__ __forceinline__

typedef __attribute__((ext_vector_type(8))) __bf16 bf16x8;
typedef __attribute__((ext_vector_type(4))) float f32x4;

DI unsigned short f2bf(float x) {
  union { float f; unsigned u; } v; v.f = x;
  unsigned r = v.u + 0x7fffu + ((v.u >> 16) & 1u);
  return (unsigned short)(r >> 16);
}
DI float bf2f(unsigned short h) {
  union { unsigned u; float f; } v; v.u = ((unsigned)h) << 16;
  return v.f;
}
DI unsigned pack2(float a, float b) {
  return (unsigned)f2bf(a) | (((unsigned)f2bf(b)) << 16);
}

// ---------------------------------------------------------------------------
// K1: tg[b,o,n] = sum_c Wcat[o,c] * y[b,c,n]   (o<256: w_theta, o>=256: w_g)
// bf16 MFMA 16x16x32, 128x128 tile, BK=32. Output bf16.
// ---------------------------------------------------------------------------
__global__ __launch_bounds__(256) void k1_conv_tg(
    const float* __restrict__ y, const float* __restrict__ w_theta,
    const float* __restrict__ w_g, unsigned short* __restrict__ tg)
{
  const int tid = threadIdx.x;
  const int nb = blockIdx.x * 128;
  const int mb = blockIdx.y * 128;
  const int b  = blockIdx.z;
  const int lane = tid & 63, wv = tid >> 6;
  const int wm = (wv & 1) * 64, wn = (wv >> 1) * 64;
  const int l15 = lane & 15, l4 = lane >> 4;

  __shared__ unsigned short Ah[128 * 40];
  __shared__ unsigned short Bt[128 * 40];

  f32x4 acc[4][4];
  #pragma unroll
  for (int i = 0; i < 4; ++i)
    #pragma unroll
    for (int j = 0; j < 4; ++j) acc[i][j] = f32x4{0.f, 0.f, 0.f, 0.f};

  for (int kb = 0; kb < 512; kb += 32) {
    // stage A: weights [128 rows o][32 k]
    #pragma unroll
    for (int j = 0; j < 4; ++j) {
      int flat = tid + 256 * j;
      int row = flat >> 3, c4 = (flat & 7) << 2;
      int og = mb + row;
      const float* wr = (og < 256) ? (w_theta + (size_t)og * 512)
                                   : (w_g + (size_t)(og - 256) * 512);
      float4 v = *(const float4*)(wr + kb + c4);
      uint2 u; u.x = pack2(v.x, v.y); u.y = pack2(v.z, v.w);
      *(uint2*)&Ah[row * 40 + c4] = u;
    }
    // stage B transposed: Bt[n][k] = y[b, kb+k, nb+n]
    #pragma unroll
    for (int j = 0; j < 2; ++j) {
      int q = tid + 256 * j;
      int cp = q >> 5, n4 = (q & 31) << 2;
      const float* yr = y + ((size_t)(b * 512 + kb) + cp * 2) * 4096 + nb + n4;
      float4 r0 = *(const float4*)yr;
      float4 r1 = *(const float4*)(yr + 4096);
      const float* p0 = (const float*)&r0;
      const float* p1 = (const float*)&r1;
      #pragma unroll
      for (int i = 0; i < 4; ++i)
        *(unsigned*)&Bt[(n4 + i) * 40 + cp * 2] = pack2(p0[i], p1[i]);
    }
    __syncthreads();
    bf16x8 af[4], bfr[4];
    #pragma unroll
    for (int i = 0; i < 4; ++i)
      af[i] = *(const bf16x8*)&Ah[(wm + i * 16 + l15) * 40 + l4 * 8];
    #pragma unroll
    for (int j = 0; j < 4; ++j)
      bfr[j] = *(const bf16x8*)&Bt[(wn + j * 16 + l15) * 40 + l4 * 8];
    #pragma unroll
    for (int i = 0; i < 4; ++i)
      #pragma unroll
      for (int j = 0; j < 4; ++j)
        acc[i][j] = __builtin_amdgcn_mfma_f32_16x16x32_bf16(af[i], bfr[j], acc[i][j], 0, 0, 0);
    __syncthreads();
  }

  #pragma unroll
  for (int i = 0; i < 4; ++i)
    #pragma unroll
    for (int j = 0; j < 4; ++j)
      #pragma unroll
      for (int r = 0; r < 4; ++r) {
        int o = mb + wm + i * 16 + l4 * 4 + r;
        int n = nb + wn + j * 16 + l15;
        tg[((size_t)(b * 512) + o) * 4096 + n] = f2bf(acc[i][j][r]);
      }
}

// ---------------------------------------------------------------------------
// K2: SPP adaptive-max-pool of one (b, channel) 64x64 plane -> 110 bins (+pad)
// Pt[b][s][ic] (theta, o<256), Pg[b][s][ic] (g, o>=256); rows 110..127 zeroed.
// ---------------------------------------------------------------------------
__constant__ int c_RS[18] = {0, 0,21,42, 0,10,21,32,42,53, 0,8,16,24,32,40,48,56};
__constant__ int c_RE[18] = {64, 22,43,64, 11,22,32,43,54,64, 8,16,24,32,40,48,56,64};

__global__ __launch_bounds__(256) void k2_spp(
    const unsigned short* __restrict__ tg, float* __restrict__ Pt,
    float* __restrict__ Pg)
{
  const int o = blockIdx.x, b = blockIdx.y, tid = threadIdx.x;
  __shared__ float L[64 * 68];
  __shared__ float R[18 * 68];
  const unsigned short* p = tg + ((size_t)(b * 512) + o) * 4096;
  #pragma unroll
  for (int j = 0; j < 2; ++j) {
    int base = tid * 16 + j * 8;
    uint4 u = *(const uint4*)(p + base);
    int h = base >> 6, w = base & 63;
    float* d = &L[h * 68 + w];
    d[0] = bf2f((unsigned short)(u.x & 0xffff)); d[1] = bf2f((unsigned short)(u.x >> 16));
    d[2] = bf2f((unsigned short)(u.y & 0xffff)); d[3] = bf2f((unsigned short)(u.y >> 16));
    d[4] = bf2f((unsigned short)(u.z & 0xffff)); d[5] = bf2f((unsigned short)(u.z >> 16));
    d[6] = bf2f((unsigned short)(u.w & 0xffff)); d[7] = bf2f((unsigned short)(u.w >> 16));
  }
  __syncthreads();
  for (int t = tid; t < 18 * 64; t += 256) {
    int rb = t >> 6, w = t & 63;
    float m = -3.4e38f;
    int e = c_RE[rb];
    for (int h = c_RS[rb]; h < e; ++h) m = fmaxf(m, L[h * 68 + w]);
    R[rb * 68 + w] = m;
  }
  __syncthreads();
  if (tid < 128) {
    float val = 0.f;
    if (tid < 110) {
      int t = tid, rb, cb;
      if (t == 0)      { rb = 0; cb = 0; }
      else if (t < 10) { int i = t - 1;  rb = 1 + i / 3;  cb = 1 + i % 3; }
      else if (t < 46) { int i = t - 10; rb = 4 + i / 6;  cb = 4 + i % 6; }
      else             { int i = t - 46; rb = 10 + i / 8; cb = 10 + i % 8; }
      float m = -3.4e38f;
      int e = c_RE[cb];
      for (int w = c_RS[cb]; w < e; ++w) m = fmaxf(m, R[rb * 68 + w]);
      val = m;
    }
    float* outp = (o < 256) ? Pt : Pg;
    int ch = (o < 256) ? o : (o - 256);
    outp[((size_t)(b * 128) + tid) * 256 + ch] = val;
  }
}

// ---------------------------------------------------------------------------
// K3a: Kt[b,s,c] = sum_ic w_phi[ic,c] * Pt[b,s,ic]  (fp32 VALU), write split
// bf16 hi/lo for the precision-critical scores GEMM.
// ---------------------------------------------------------------------------
__global__ __launch_bounds__(256) void k3_kmat(
    const float* __restrict__ Pt, const float* __restrict__ w_phi,
    unsigned short* __restrict__ Kth, unsigned short* __restrict__ Ktl)
{
  const int ct = blockIdx.x, b = blockIdx.y, tid = threadIdx.x;
  const int tx = tid & 15, ty = tid >> 4;
  const int c0 = tx * 4, s0 = ty * 8;
  __shared__ float Ls[128 * 64];
  __shared__ float Ws[64 * 68];
  float acc[8][4] = {};
  for (int kc = 0; kc < 256; kc += 64) {
    #pragma unroll
    for (int j = 0; j < 8; ++j) {
      int flat = tid + 256 * j;
      int row = flat >> 4, k4 = (flat & 15) << 2;
      *(float4*)&Ls[row * 64 + k4] =
          *(const float4*)(Pt + ((size_t)(b * 128) + row) * 256 + kc + k4);
    }
    #pragma unroll
    for (int j = 0; j < 4; ++j) {
      int flat = tid + 256 * j;
      int row = flat >> 4, c4 = (flat & 15) << 2;
      *(float4*)&Ws[row * 68 + c4] =
          *(const float4*)(w_phi + (size_t)(kc + row) * 512 + ct * 64 + c4);
    }
    __syncthreads();
    for (int k = 0; k < 64; k += 4) {
      float4 wv[4];
      #pragma unroll
      for (int kk = 0; kk < 4; ++kk) wv[kk] = *(const float4*)&Ws[(k + kk) * 68 + c0];
      #pragma unroll
      for (int i = 0; i < 8; ++i) {
        float4 a = *(const float4*)&Ls[(s0 + i) * 64 + k];
        const float* ap = (const float*)&a;
        #pragma unroll
        for (int kk = 0; kk < 4; ++kk) {
          const float* wp = (const float*)&wv[kk];
          acc[i][0] += ap[kk] * wp[0];
          acc[i][1] += ap[kk] * wp[1];
          acc[i][2] += ap[kk] * wp[2];
          acc[i][3] += ap[kk] * wp[3];
        }
      }
    }
    __syncthreads();
  }
  #pragma unroll
  for (int i = 0; i < 8; ++i) {
    unsigned short hi[4]; float lo[4];
    #pragma unroll
    for (int j = 0; j < 4; ++j) { hi[j] = f2bf(acc[i][j]); lo[j] = acc[i][j] - bf2f(hi[j]); }
    size_t base = ((size_t)(b * 128) + s0 + i) * 512 + ct * 64 + c0;
    uint2 uh; uh.x = (unsigned)hi[0] | ((unsigned)hi[1] << 16);
    uh.y = (unsigned)hi[2] | ((unsigned)hi[3] << 16);
    uint2 ul; ul.x = pack2(lo[0], lo[1]); ul.y = pack2(lo[2], lo[3]);
    *(uint2*)&Kth[base] = uh;
    *(uint2*)&Ktl[base] = ul;
  }
}

// ---------------------------------------------------------------------------
// K3b: V[b,o,s] = sum_ic w_mask[o,ic] * Pg[b,s,ic]  (fp32 VALU)
// ---------------------------------------------------------------------------
__global__ __launch_bounds__(256) void k3_vmat(
    const float* __restrict__ Pg, const float* __restrict__ w_mask,
    float* __restrict__ V)
{
  const int ot = blockIdx.x, b = blockIdx.y, tid = threadIdx.x;
  const int tx = tid & 15, ty = tid >> 4;
  const int o0 = ty * 4;
  __shared__ float Ws[64 * 64];
  __shared__ float Ps[128 * 68];
  float acc[4][8] = {};
  for (int kc = 0; kc < 256; kc += 64) {
    #pragma unroll
    for (int j = 0; j < 4; ++j) {
      int flat = tid + 256 * j;
      int row = flat >> 4, k4 = (flat & 15) << 2;
      *(float4*)&Ws[row * 64 + k4] =
          *(const float4*)(w_mask + (size_t)(ot * 64 + row) * 256 + kc + k4);
    }
    #pragma unroll
    for (int j = 0; j < 8; ++j) {
      int flat = tid + 256 * j;
      int row = flat >> 4, k4 = (flat & 15) << 2;
      *(float4*)&Ps[row * 68 + k4] =
          *(const float4*)(Pg + ((size_t)(b * 128) + row) * 256 + kc + k4);
    }
    __syncthreads();
    for (int k = 0; k < 64; k += 4) {
      float4 wv[4];
      #pragma unroll
      for (int i = 0; i < 4; ++i) wv[i] = *(const float4*)&Ws[(o0 + i) * 64 + k];
      #pragma unroll
      for (int jj = 0; jj < 8; ++jj) {
        float4 pv = *(const float4*)&Ps[(tx + 16 * jj) * 68 + k];
        const float* pp = (const float*)&pv;
        #pragma unroll
        for (int i = 0; i < 4; ++i) {
          const float* wp = (const float*)&wv[i];
          #pragma unroll
          for (int kk = 0; kk < 4; ++kk) acc[i][jj] += wp[kk] * pp[kk];
        }
      }
    }
    __syncthreads();
  }
  #pragma unroll
  for (int i = 0; i < 4; ++i)
    #pragma unroll
    for (int jj = 0; jj < 8; ++jj)
      V[((size_t)(b * 512) + ot * 64 + o0 + i) * 128 + tx + 16 * jj] = acc[i][jj];
}

// ---------------------------------------------------------------------------
// K4: scores[b,s,n] = sum_c Kt[b,s,c] * x[b,c,n]  — split-bf16 (hi/lo both
// operands, 3 MFMAs) for softmax-safe precision. scores fp32 [B,128,N].
// ---------------------------------------------------------------------------
__global__ __launch_bounds__(256) void k4_scores(
    const float* __restrict__ x, const unsigned short* __restrict__ Kth,
    const unsigned short* __restrict__ Ktl, float* __restrict__ scores)
{
  const int tid = threadIdx.x;
  const int nb = blockIdx.x * 128;
  const int b = blockIdx.y;
  const int lane = tid & 63, wv = tid >> 6;
  const int wm = (wv & 1) * 64, wn = (wv >> 1) * 64;
  const int l15 = lane & 15, l4 = lane >> 4;
  __shared__ unsigned short Ah[128 * 40], Al[128 * 40];
  __shared__ unsigned short Bh[128 * 40], Bl[128 * 40];
  f32x4 acc[4][4];
  #pragma unroll
  for (int i = 0; i < 4; ++i)
    #pragma unroll
    for (int j = 0; j < 4; ++j) acc[i][j] = f32x4{0.f, 0.f, 0.f, 0.f};

  for (int kb = 0; kb < 512; kb += 32) {
    // FIX R1: j<4 (was j<2) — must cover all 128 rows of Ah/Al each K-step.
    #pragma unroll
    for (int j = 0; j < 4; ++j) {
      int flat = tid + 256 * j;
      int row = flat >> 3, c4 = (flat & 7) << 2;
      size_t g = ((size_t)(b * 128) + row) * 512 + kb + c4;
      *(uint2*)&Ah[row * 40 + c4] = *(const uint2*)(Kth + g);
      *(uint2*)&Al[row * 40 + c4] = *(const uint2*)(Ktl + g);
    }
    #pragma unroll
    for (int j = 0; j < 2; ++j) {
      int q = tid + 256 * j;
      int cp = q >> 5, n4 = (q & 31) << 2;
      const float* xr = x + ((size_t)(b * 512 + kb) + cp * 2) * 4096 + nb + n4;
      float4 r0 = *(const float4*)xr;
      float4 r1 = *(const float4*)(xr + 4096);
      const float* p0 = (const float*)&r0;
      const float* p1 = (const float*)&r1;
      #pragma unroll
      for (int i = 0; i < 4; ++i) {
        unsigned short h0 = f2bf(p0[i]), h1 = f2bf(p1[i]);
        *(unsigned*)&Bh[(n4 + i) * 40 + cp * 2] = (unsigned)h0 | ((unsigned)h1 << 16);
        *(unsigned*)&Bl[(n4 + i) * 40 + cp * 2] = pack2(p0[i] - bf2f(h0), p1[i] - bf2f(h1));
      }
    }
    __syncthreads();
    bf16x8 ah[4], al[4], bh[4], bl[4];
    #pragma unroll
    for (int i = 0; i < 4; ++i) {
      ah[i] = *(const bf16x8*)&Ah[(wm + i * 16 + l15) * 40 + l4 * 8];
      al[i] = *(const bf16x8*)&Al[(wm + i * 16 + l15) * 40 + l4 * 8];
    }
    #pragma unroll
    for (int j = 0; j < 4; ++j) {
      bh[j] = *(const bf16x8*)&Bh[(wn + j * 16 + l15) * 40 + l4 * 8];
      bl[j] = *(const bf16x8*)&Bl[(wn + j * 16 + l15) * 40 + l4 * 8];
    }
    #pragma unroll
    for (int i = 0; i < 4; ++i)
      #pragma unroll
      for (int j = 0; j < 4; ++j) {
        acc[i][j] = __builtin_amdgcn_mfma_f32_16x16x32_bf16(ah[i], bh[j], acc[i][j], 0, 0, 0);
        acc[i][j] = __builtin_amdgcn_mfma_f32_16x16x32_bf16(ah[i], bl[j], acc[i][j], 0, 0, 0);
        acc[i][j] = __builtin_amdgcn_mfma_f32_16x16x32_bf16(al[i], bh[j], acc[i][j], 0, 0, 0);
      }
    __syncthreads();
  }
  #pragma unroll
  for (int i = 0; i < 4; ++i)
    #pragma unroll
    for (int j = 0; j < 4; ++j)
      #pragma unroll
      for (int r = 0; r < 4; ++r)
        scores[((size_t)(b * 128) + wm + i * 16 + l4 * 4 + r) * 4096 + nb + wn + j * 16 + l15] =
            acc[i][j][r];
}

// ---------------------------------------------------------------------------
// K5: per-(b,s) softmax stats over N=4096: m = max, linv = 1/sum(exp(v-m))
// ---------------------------------------------------------------------------
__global__ __launch_bounds__(256) void k5_stats(
    const float* __restrict__ scores, float* __restrict__ mbuf,
    float* __restrict__ lbuf)
{
  const int s = blockIdx.x, b = blockIdx.y, tid = threadIdx.x;
  if (s >= 110) {
    if (tid == 0) { mbuf[b * 128 + s] = 0.f; lbuf[b * 128 + s] = 0.f; }
    return;
  }
  const float* row = scores + ((size_t)(b * 128) + s) * 4096;
  float4 v[4];
  float m = -3.4e38f;
  #pragma unroll
  for (int j = 0; j < 4; ++j) {
    v[j] = *(const float4*)(row + (tid + 256 * j) * 4);
    m = fmaxf(m, fmaxf(fmaxf(v[j].x, v[j].y), fmaxf(v[j].z, v[j].w)));
  }
  #pragma unroll
  for (int off = 32; off > 0; off >>= 1) m = fmaxf(m, __shfl_down(m, off));
  __shared__ float red[8];
  if ((tid & 63) == 0) red[tid >> 6] = m;
  __syncthreads();
  float mm = fmaxf(fmaxf(red[0], red[1]), fmaxf(red[2], red[3]));
  float sum = 0.f;
  #pragma unroll
  for (int j = 0; j < 4; ++j)
    sum += __expf(v[j].x - mm) + __expf(v[j].y - mm) +
           __expf(v[j].z - mm) + __expf(v[j].w - mm);
  #pragma unroll
  for (int off = 32; off > 0; off >>= 1) sum += __shfl_down(sum, off);
  if ((tid & 63) == 0) red[4 + (tid >> 6)] = sum;
  __syncthreads();
  if (tid == 0) {
    float S = red[4] + red[5] + red[6] + red[7];
    mbuf[b * 128 + s] = mm;
    lbuf[b * 128 + s] = 1.f / S;
  }
}

// ---------------------------------------------------------------------------
// K5E: Eb[b,n,s] = bf16(exp(scores[b,s,n] - m[b,s]))  (transpose + exp)
// tile: 128 s x 64 n per block.
// ---------------------------------------------------------------------------
__global__ __launch_bounds__(256) void k5e_expT(
    const float* __restrict__ scores, const float* __restrict__ mbuf,
    unsigned short* __restrict__ Eb)
{
  const int nt = blockIdx.x, b = blockIdx.y, tid = threadIdx.x;
  __shared__ float L[128 * 68];
  __shared__ float sm[128];
  if (tid < 128) sm[tid] = mbuf[b * 128 + tid];
  #pragma unroll
  for (int j = 0; j < 8; ++j) {
    int flat = tid + 256 * j;
    int s = flat >> 4, n4 = (flat & 15) << 2;
    *(float4*)&L[s * 68 + n4] =
        *(const float4*)(scores + ((size_t)(b * 128) + s) * 4096 + nt * 64 + n4);
  }
  __syncthreads();
  int n = tid >> 2, sq = (tid & 3) * 32;
  unsigned ub[16];
  #pragma unroll
  for (int k = 0; k < 32; k += 2) {
    float e0 = __expf(L[(sq + k) * 68 + n] - sm[sq + k]);
    float e1 = __expf(L[(sq + k + 1) * 68 + n] - sm[sq + k + 1]);
    ub[k >> 1] = pack2(e0, e1);
  }
  uint4* dst = (uint4*)(Eb + ((size_t)(b * 4096) + nt * 64 + n) * 128 + sq);
  #pragma unroll
  for (int j = 0; j < 4; ++j)
    dst[j] = make_uint4(ub[4 * j], ub[4 * j + 1], ub[4 * j + 2], ub[4 * j + 3]);
}

// ---------------------------------------------------------------------------
// K6: out[b,o,n] = sum_s (V[b,o,s]*linv[b,s]) * Eb[b,n,s] + x[b,o,n]
// bf16 MFMA, K=128 (zero-padded s), k-chunked staging (LDS <= 40KB).
// ---------------------------------------------------------------------------
__global__ __launch_bounds__(256) void k6_out(
    const unsigned short* __restrict__ Eb, const float* __restrict__ V,
    const float* __restrict__ lbuf, const float* __restrict__ x,
    float* __restrict__ out)
{
  const int tid = threadIdx.x;
  const int nb = blockIdx.x * 128;
  const int mb = blockIdx.y * 128;
  const int b = blockIdx.z;
  const int lane = tid & 63, wv = tid >> 6;
  const int wm = (wv & 1) * 64, wn = (wv >> 1) * 64;
  const int l15 = lane & 15, l4 = lane >> 4;
  __shared__ unsigned short Ah[128 * 72];
  __shared__ unsigned short Bt[128 * 72];
  __shared__ float sl[128];
  if (tid < 128) sl[tid] = lbuf[b * 128 + tid];

  f32x4 acc[4][4];
  #pragma unroll
  for (int i = 0; i < 4; ++i)
    #pragma unroll
    for (int j = 0; j < 4; ++j) acc[i][j] = f32x4{0.f, 0.f, 0.f, 0.f};

  for (int kc = 0; kc < 128; kc += 64) {
    __syncthreads();
    #pragma unroll
    for (int j = 0; j < 8; ++j) {
      int flat = tid + 256 * j;
      int row = flat >> 4, s4 = (flat & 15) << 2;
      float4 v = *(const float4*)(V + ((size_t)(b * 512) + mb + row) * 128 + kc + s4);
      v.x *= sl[kc + s4]; v.y *= sl[kc + s4 + 1];
      v.z *= sl[kc + s4 + 2]; v.w *= sl[kc + s4 + 3];
      uint2 u; u.x = pack2(v.x, v.y); u.y = pack2(v.z, v.w);
      *(uint2*)&Ah[row * 72 + s4] = u;
    }
    #pragma unroll
    for (int j = 0; j < 4; ++j) {
      int flat = tid + 256 * j;
      int n = flat >> 3, s8 = (flat & 7) << 3;
      uint4 u = *(const uint4*)(Eb + ((size_t)(b * 4096) + nb + n) * 128 + kc + s8);
      *(uint4*)&Bt[n * 72 + s8] = u;
    }
    __syncthreads();
    #pragma unroll
    for (int kb = 0; kb < 64; kb += 32) {
      bf16x8 af[4], bfr[4];
      #pragma unroll
      for (int i = 0; i < 4; ++i)
        af[i] = *(const bf16x8*)&Ah[(wm + i * 16 + l15) * 72 + kb + l4 * 8];
      #pragma unroll
      for (int j = 0; j < 4; ++j)
        bfr[j] = *(const bf16x8*)&Bt[(wn + j * 16 + l15) * 72 + kb + l4 * 8];
      #pragma unroll
      for (int i = 0; i < 4; ++i)
        #pragma unroll
        for (int j = 0; j < 4; ++j)
          acc[i][j] = __builtin_amdgcn_mfma_f32_16x16x32_bf16(af[i], bfr[j], acc[i][j], 0, 0, 0);
    }
  }
  #pragma unroll
  for (int i = 0; i < 4; ++i)
    #pragma unroll
    for (int j = 0; j < 4; ++j)
      #pragma unroll
      for (int r = 0; r < 4; ++r) {
        int o = mb + wm + i * 16 + l4 * 4 + r;
        size_t idx = ((size_t)(b * 512) + o) * 4096 + nb + wn + j * 16 + l15;
        out[idx] = acc[i][j][r] + x[idx];
      }
}

// ---------------------------------------------------------------------------
extern "C" void kernel_launch(void* const* d_in, const int* in_sizes, int n_in,
                              void* d_out, int out_size, void* d_ws, size_t ws_size,
                              hipStream_t stream)
{
  (void)in_sizes; (void)n_in; (void)out_size; (void)ws_size;
  const float* x       = (const float*)d_in[0];
  const float* y       = (const float*)d_in[1];
  const float* w_phi   = (const float*)d_in[2];
  const float* w_theta = (const float*)d_in[3];
  const float* w_g     = (const float*)d_in[4];
  const float* w_mask  = (const float*)d_in[5];
  float* out = (float*)d_out;

  char* ws = (char*)d_ws;
  unsigned short* tg  = (unsigned short*)ws; ws += 67108864;  // [16,512,4096] bf16
  float* scores       = (float*)ws;          ws += 33554432;  // [16,128,4096] f32
  float* Pt           = (float*)ws;          ws += 2097152;   // [16,128,256]  f32
  float* Pg           = (float*)ws;          ws += 2097152;   // [16,128,256]  f32
  unsigned short* Kth = (unsigned short*)ws; ws += 2097152;   // [16,128,512]  bf16
  unsigned short* Ktl = (unsigned short*)ws; ws += 2097152;   // [16,128,512]  bf16
  float* V            = (float*)ws;          ws += 4194304;   // [16,512,128]  f32
  float* mbuf         = (float*)ws;          ws += 8192;      // [16,128]
  float* lbuf         = (float*)ws;          ws += 8192;      // [16,128]
  unsigned short* Eb  = (unsigned short*)ws; ws += 16777216;  // [16,4096,128] bf16

  k1_conv_tg<<<dim3(32, 4, 16), 256, 0, stream>>>(y, w_theta, w_g, tg);
  k2_spp<<<dim3(512, 16), 256, 0, stream>>>(tg, Pt, Pg);
  k3_kmat<<<dim3(8, 16), 256, 0, stream>>>(Pt, w_phi, Kth, Ktl);
  k3_vmat<<<dim3(8, 16), 256, 0, stream>>>(Pg, w_mask, V);
  k4_scores<<<dim3(32, 16), 256, 0, stream>>>(x, Kth, Ktl, scores);
  k5_stats<<<dim3(128, 16), 256, 0, stream>>>(scores, mbuf, lbuf);
  k5e_expT<<<dim3(64, 16), 256, 0, stream>>>(scores, mbuf, Eb);
  k6_out<<<dim3(32, 4, 16), 256, 0, stream>>>(Eb, V, lbuf, x, out);
}

// Round 3
// 561.416 us; speedup vs baseline: 1.0483x; 1.0483x over previous
//
#include <hip/hip_runtime.h>

#define DI __device__ __forceinline__

typedef __attribute__((ext_vector_type(8))) __bf16 bf16x8;
typedef __attribute__((ext_vector_type(4))) float f32x4;

DI unsigned short f2bf(float x) {
  union { float f; unsigned u; } v; v.f = x;
  unsigned r = v.u + 0x7fffu + ((v.u >> 16) & 1u);
  return (unsigned short)(r >> 16);
}
DI float bf2f(unsigned short h) {
  union { unsigned u; float f; } v; v.u = ((unsigned)h) << 16;
  return v.f;
}
DI unsigned pack2(float a, float b) {
  return (unsigned)f2bf(a) | (((unsigned)f2bf(b)) << 16);
}

// ---------------------------------------------------------------------------
// P0: transpose-convert [b][512 c][4096 n] f32 -> [b][4096 n][512 c] bf16.
// 64x64 tiles via LDS (stride 65: verified conflict-free both sides).
// ---------------------------------------------------------------------------
__global__ __launch_bounds__(256) void p0_transpose(
    const float* __restrict__ src, unsigned short* __restrict__ dst)
{
  const int n0 = blockIdx.x * 64, c0 = blockIdx.y * 64, b = blockIdx.z;
  const int tid = threadIdx.x;
  __shared__ float T[64 * 65];
  #pragma unroll
  for (int p = 0; p < 4; ++p) {
    int r = p * 16 + (tid >> 4);
    int n4 = (tid & 15) << 2;
    *(float4*)&T[r * 65 + n4] =
        *(const float4*)(src + ((size_t)(b * 512 + c0 + r)) * 4096 + n0 + n4);
  }
  __syncthreads();
  int n = tid >> 2, cc = (tid & 3) * 16;
  unsigned u[8];
  #pragma unroll
  for (int j = 0; j < 16; j += 2)
    u[j >> 1] = pack2(T[(cc + j) * 65 + n], T[(cc + j + 1) * 65 + n]);
  unsigned short* d = dst + ((size_t)(b * 4096 + n0 + n)) * 512 + c0 + cc;
  *(uint4*)(d) = make_uint4(u[0], u[1], u[2], u[3]);
  *(uint4*)(d + 8) = make_uint4(u[4], u[5], u[6], u[7]);
}

// ---------------------------------------------------------------------------
// K1F: conv (theta|g) for a 128o x 128n tile via bf16 MFMA from pre-transposed
// yT, then fused SPP w-bin pooling epilogue -> Rbuf[b][64 h][18 wbin][512 ch].
// 128n = 2 image rows (h = blockIdx.y*2 + pass). No tg materialization.
// ---------------------------------------------------------------------------
__constant__ int c_RS[18] = {0, 0,21,42, 0,10,21,32,42,53, 0,8,16,24,32,40,48,56};
__constant__ int c_RE[18] = {64, 22,43,64, 11,22,32,43,54,64, 8,16,24,32,40,48,56,64};

__global__ __launch_bounds__(256) void k1f_conv_pool(
    const unsigned short* __restrict__ yT, const float* __restrict__ w_theta,
    const float* __restrict__ w_g, unsigned short* __restrict__ Rbuf)
{
  const int tid = threadIdx.x;
  const int mb = blockIdx.x * 128;   // output channel tile (fastest -> yT L2 reuse)
  const int nb = blockIdx.y * 128;   // spatial tile
  const int b  = blockIdx.z;
  const int lane = tid & 63, wv = tid >> 6;
  const int wm = (wv & 1) * 64, wn = (wv >> 1) * 64;
  const int l15 = lane & 15, l4 = lane >> 4;

  __shared__ __align__(16) char smem[33280];   // union: staging 20.5KB | epi 33.3KB
  unsigned short* As = (unsigned short*)smem;
  unsigned short* Bs = (unsigned short*)(smem + 10240);
  float* P = (float*)smem;

  f32x4 acc[4][4];
  #pragma unroll
  for (int i = 0; i < 4; ++i)
    #pragma unroll
    for (int j = 0; j < 4; ++j) acc[i][j] = f32x4{0.f, 0.f, 0.f, 0.f};

  for (int kb = 0; kb < 512; kb += 32) {
    // A: weights fp32 -> bf16 (conflict-free uint2 pattern)
    #pragma unroll
    for (int j = 0; j < 4; ++j) {
      int flat = tid + 256 * j;
      int row = flat >> 3, c4 = (flat & 7) << 2;
      int og = mb + row;
      const float* wr = (og < 256) ? (w_theta + (size_t)og * 512)
                                   : (w_g + (size_t)(og - 256) * 512);
      float4 v = *(const float4*)(wr + kb + c4);
      uint2 u; u.x = pack2(v.x, v.y); u.y = pack2(v.z, v.w);
      *(uint2*)&As[row * 40 + c4] = u;
    }
    // B: yT bf16 straight copy, b128 writes (uniform banks -> conflict-free)
    #pragma unroll
    for (int p = 0; p < 2; ++p) {
      int q = tid + 256 * p;
      int row = q >> 2, s8 = (q & 3) << 3;
      *(uint4*)&Bs[row * 40 + s8] =
          *(const uint4*)(yT + ((size_t)(b * 4096 + nb + row)) * 512 + kb + s8);
    }
    __syncthreads();
    bf16x8 af[4], bfr[4];
    #pragma unroll
    for (int i = 0; i < 4; ++i)
      af[i] = *(const bf16x8*)&As[(wm + i * 16 + l15) * 40 + l4 * 8];
    #pragma unroll
    for (int j = 0; j < 4; ++j)
      bfr[j] = *(const bf16x8*)&Bs[(wn + j * 16 + l15) * 40 + l4 * 8];
    #pragma unroll
    for (int i = 0; i < 4; ++i)
      #pragma unroll
      for (int j = 0; j < 4; ++j)
        acc[i][j] = __builtin_amdgcn_mfma_f32_16x16x32_bf16(af[i], bfr[j], acc[i][j], 0, 0, 0);
    __syncthreads();
  }

  // Fused pooling epilogue: two passes (n-halves = image rows h, h+1).
  const int hloc = wv >> 1;
  #pragma unroll
  for (int pass = 0; pass < 2; ++pass) {
    __syncthreads();
    if (hloc == pass) {
      #pragma unroll
      for (int i = 0; i < 4; ++i)
        #pragma unroll
        for (int j = 0; j < 4; ++j)
          #pragma unroll
          for (int r = 0; r < 4; ++r)
            P[(wm + i * 16 + l4 * 4 + r) * 65 + j * 16 + l15] = acc[i][j][r];
    }
    __syncthreads();
    const int o = tid & 127;
    size_t rbase = (((size_t)(b * 64 + blockIdx.y * 2 + pass)) * 18) * 512 + mb + o;
    if (tid < 128) {
      // levels 1 and 3 (w-bins 0..3)
      float b0 = -3.4e38f, b1 = b0, b2 = b0, b3 = b0;
      #pragma unroll
      for (int w = 0; w < 64; ++w) {
        float v = P[o * 65 + w];
        b0 = fmaxf(b0, v);
        if (w < 22) b1 = fmaxf(b1, v);
        if (w >= 21 && w < 43) b2 = fmaxf(b2, v);
        if (w >= 42) b3 = fmaxf(b3, v);
      }
      Rbuf[rbase]           = f2bf(b0);
      Rbuf[rbase + 512]     = f2bf(b1);
      Rbuf[rbase + 2 * 512] = f2bf(b2);
      Rbuf[rbase + 3 * 512] = f2bf(b3);
    } else {
      // levels 6 and 8 (w-bins 4..17)
      float s6[6], s8[8];
      #pragma unroll
      for (int i = 0; i < 6; ++i) s6[i] = -3.4e38f;
      #pragma unroll
      for (int i = 0; i < 8; ++i) s8[i] = -3.4e38f;
      constexpr int R6S[6] = {0, 10, 21, 32, 42, 53};
      constexpr int R6E[6] = {11, 22, 32, 43, 54, 64};
      #pragma unroll
      for (int w = 0; w < 64; ++w) {
        float v = P[o * 65 + w];
        #pragma unroll
        for (int i = 0; i < 6; ++i)
          if (w >= R6S[i] && w < R6E[i]) s6[i] = fmaxf(s6[i], v);
        s8[w >> 3] = fmaxf(s8[w >> 3], v);
      }
      #pragma unroll
      for (int i = 0; i < 6; ++i) Rbuf[rbase + (size_t)(4 + i) * 512] = f2bf(s6[i]);
      #pragma unroll
      for (int i = 0; i < 8; ++i) Rbuf[rbase + (size_t)(10 + i) * 512] = f2bf(s8[i]);
    }
  }
}

// ---------------------------------------------------------------------------
// K2F: reduce Rbuf over h within each pyramid h-bin -> Pt/Pg [b][128 s][256].
// Rows s >= 110 zeroed (required by downstream K/score/exp path).
// ---------------------------------------------------------------------------
__global__ __launch_bounds__(256) void k2_pool_final(
    const unsigned short* __restrict__ Rbuf, float* __restrict__ Pt,
    float* __restrict__ Pg)
{
  const int s = blockIdx.x, b = blockIdx.y, tid = threadIdx.x;
  size_t obase = ((size_t)(b * 128) + s) * 256 + tid;
  if (s >= 110) { Pt[obase] = 0.f; Pg[obase] = 0.f; return; }
  int he, wb;
  if (s == 0)      { he = 0; wb = 0; }
  else if (s < 10) { int i = s - 1;  he = 1 + i / 3;  wb = 1 + i % 3; }
  else if (s < 46) { int i = s - 10; he = 4 + i / 6;  wb = 4 + i % 6; }
  else             { int i = s - 46; he = 10 + i / 8; wb = 10 + i % 8; }
  float m0 = -3.4e38f, m1 = -3.4e38f;
  int e = c_RE[he];
  for (int h = c_RS[he]; h < e; ++h) {
    const unsigned short* r = Rbuf + (((size_t)(b * 64 + h)) * 18 + wb) * 512;
    m0 = fmaxf(m0, bf2f(r[tid]));
    m1 = fmaxf(m1, bf2f(r[tid + 256]));
  }
  Pt[obase] = m0;
  Pg[obase] = m1;
}

// ---------------------------------------------------------------------------
// K3a: Kt[b,s,c] = sum_ic w_phi[ic,c] * Pt[b,s,ic]  (fp32 VALU), split hi/lo.
// ---------------------------------------------------------------------------
__global__ __launch_bounds__(256) void k3_kmat(
    const float* __restrict__ Pt, const float* __restrict__ w_phi,
    unsigned short* __restrict__ Kth, unsigned short* __restrict__ Ktl)
{
  const int ct = blockIdx.x, b = blockIdx.y, tid = threadIdx.x;
  const int tx = tid & 15, ty = tid >> 4;
  const int c0 = tx * 4, s0 = ty * 8;
  __shared__ float Ls[128 * 64];
  __shared__ float Ws[64 * 68];
  float acc[8][4] = {};
  for (int kc = 0; kc < 256; kc += 64) {
    #pragma unroll
    for (int j = 0; j < 8; ++j) {
      int flat = tid + 256 * j;
      int row = flat >> 4, k4 = (flat & 15) << 2;
      *(float4*)&Ls[row * 64 + k4] =
          *(const float4*)(Pt + ((size_t)(b * 128) + row) * 256 + kc + k4);
    }
    #pragma unroll
    for (int j = 0; j < 4; ++j) {
      int flat = tid + 256 * j;
      int row = flat >> 4, c4 = (flat & 15) << 2;
      *(float4*)&Ws[row * 68 + c4] =
          *(const float4*)(w_phi + (size_t)(kc + row) * 512 + ct * 64 + c4);
    }
    __syncthreads();
    for (int k = 0; k < 64; k += 4) {
      float4 wv[4];
      #pragma unroll
      for (int kk = 0; kk < 4; ++kk) wv[kk] = *(const float4*)&Ws[(k + kk) * 68 + c0];
      #pragma unroll
      for (int i = 0; i < 8; ++i) {
        float4 a = *(const float4*)&Ls[(s0 + i) * 64 + k];
        const float* ap = (const float*)&a;
        #pragma unroll
        for (int kk = 0; kk < 4; ++kk) {
          const float* wp = (const float*)&wv[kk];
          acc[i][0] += ap[kk] * wp[0];
          acc[i][1] += ap[kk] * wp[1];
          acc[i][2] += ap[kk] * wp[2];
          acc[i][3] += ap[kk] * wp[3];
        }
      }
    }
    __syncthreads();
  }
  #pragma unroll
  for (int i = 0; i < 8; ++i) {
    unsigned short hi[4]; float lo[4];
    #pragma unroll
    for (int j = 0; j < 4; ++j) { hi[j] = f2bf(acc[i][j]); lo[j] = acc[i][j] - bf2f(hi[j]); }
    size_t base = ((size_t)(b * 128) + s0 + i) * 512 + ct * 64 + c0;
    uint2 uh; uh.x = (unsigned)hi[0] | ((unsigned)hi[1] << 16);
    uh.y = (unsigned)hi[2] | ((unsigned)hi[3] << 16);
    uint2 ul; ul.x = pack2(lo[0], lo[1]); ul.y = pack2(lo[2], lo[3]);
    *(uint2*)&Kth[base] = uh;
    *(uint2*)&Ktl[base] = ul;
  }
}

// ---------------------------------------------------------------------------
// K3b: V[b,o,s] = sum_ic w_mask[o,ic] * Pg[b,s,ic]  (fp32 VALU)
// ---------------------------------------------------------------------------
__global__ __launch_bounds__(256) void k3_vmat(
    const float* __restrict__ Pg, const float* __restrict__ w_mask,
    float* __restrict__ V)
{
  const int ot = blockIdx.x, b = blockIdx.y, tid = threadIdx.x;
  const int tx = tid & 15, ty = tid >> 4;
  const int o0 = ty * 4;
  __shared__ float Ws[64 * 64];
  __shared__ float Ps[128 * 68];
  float acc[4][8] = {};
  for (int kc = 0; kc < 256; kc += 64) {
    #pragma unroll
    for (int j = 0; j < 4; ++j) {
      int flat = tid + 256 * j;
      int row = flat >> 4, k4 = (flat & 15) << 2;
      *(float4*)&Ws[row * 64 + k4] =
          *(const float4*)(w_mask + (size_t)(ot * 64 + row) * 256 + kc + k4);
    }
    #pragma unroll
    for (int j = 0; j < 8; ++j) {
      int flat = tid + 256 * j;
      int row = flat >> 4, k4 = (flat & 15) << 2;
      *(float4*)&Ps[row * 68 + k4] =
          *(const float4*)(Pg + ((size_t)(b * 128) + row) * 256 + kc + k4);
    }
    __syncthreads();
    for (int k = 0; k < 64; k += 4) {
      float4 wv[4];
      #pragma unroll
      for (int i = 0; i < 4; ++i) wv[i] = *(const float4*)&Ws[(o0 + i) * 64 + k];
      #pragma unroll
      for (int jj = 0; jj < 8; ++jj) {
        float4 pv = *(const float4*)&Ps[(tx + 16 * jj) * 68 + k];
        const float* pp = (const float*)&pv;
        #pragma unroll
        for (int i = 0; i < 4; ++i) {
          const float* wp = (const float*)&wv[i];
          #pragma unroll
          for (int kk = 0; kk < 4; ++kk) acc[i][jj] += wp[kk] * pp[kk];
        }
      }
    }
    __syncthreads();
  }
  #pragma unroll
  for (int i = 0; i < 4; ++i)
    #pragma unroll
    for (int jj = 0; jj < 8; ++jj)
      V[((size_t)(b * 512) + ot * 64 + o0 + i) * 128 + tx + 16 * jj] = acc[i][jj];
}

// ---------------------------------------------------------------------------
// K4: scores[b,s,n] = sum_c Kt[b,s,c]*x[b,c,n]; Kt split hi/lo (2 MFMAs),
// x single-bf16 from pre-transposed xT. scores fp32 [B,128,N].
// ---------------------------------------------------------------------------
__global__ __launch_bounds__(256) void k4_scores(
    const unsigned short* __restrict__ xT, const unsigned short* __restrict__ Kth,
    const unsigned short* __restrict__ Ktl, float* __restrict__ scores)
{
  const int tid = threadIdx.x;
  const int nb = blockIdx.x * 128;
  const int b = blockIdx.y;
  const int lane = tid & 63, wv = tid >> 6;
  const int wm = (wv & 1) * 64, wn = (wv >> 1) * 64;
  const int l15 = lane & 15, l4 = lane >> 4;
  __shared__ unsigned short Ah[128 * 40], Al[128 * 40], Bs[128 * 40];
  f32x4 acc[4][4];
  #pragma unroll
  for (int i = 0; i < 4; ++i)
    #pragma unroll
    for (int j = 0; j < 4; ++j) acc[i][j] = f32x4{0.f, 0.f, 0.f, 0.f};

  for (int kb = 0; kb < 512; kb += 32) {
    #pragma unroll
    for (int p = 0; p < 2; ++p) {
      int q = tid + 256 * p;
      int row = q >> 2, s8 = (q & 3) << 3;
      size_t g = ((size_t)(b * 128) + row) * 512 + kb + s8;
      *(uint4*)&Ah[row * 40 + s8] = *(const uint4*)(Kth + g);
      *(uint4*)&Al[row * 40 + s8] = *(const uint4*)(Ktl + g);
    }
    #pragma unroll
    for (int p = 0; p < 2; ++p) {
      int q = tid + 256 * p;
      int row = q >> 2, s8 = (q & 3) << 3;
      *(uint4*)&Bs[row * 40 + s8] =
          *(const uint4*)(xT + ((size_t)(b * 4096 + nb + row)) * 512 + kb + s8);
    }
    __syncthreads();
    bf16x8 ah[4], al[4], bfr[4];
    #pragma unroll
    for (int i = 0; i < 4; ++i) {
      ah[i] = *(const bf16x8*)&Ah[(wm + i * 16 + l15) * 40 + l4 * 8];
      al[i] = *(const bf16x8*)&Al[(wm + i * 16 + l15) * 40 + l4 * 8];
    }
    #pragma unroll
    for (int j = 0; j < 4; ++j)
      bfr[j] = *(const bf16x8*)&Bs[(wn + j * 16 + l15) * 40 + l4 * 8];
    #pragma unroll
    for (int i = 0; i < 4; ++i)
      #pragma unroll
      for (int j = 0; j < 4; ++j) {
        acc[i][j] = __builtin_amdgcn_mfma_f32_16x16x32_bf16(ah[i], bfr[j], acc[i][j], 0, 0, 0);
        acc[i][j] = __builtin_amdgcn_mfma_f32_16x16x32_bf16(al[i], bfr[j], acc[i][j], 0, 0, 0);
      }
    __syncthreads();
  }
  #pragma unroll
  for (int i = 0; i < 4; ++i)
    #pragma unroll
    for (int j = 0; j < 4; ++j)
      #pragma unroll
      for (int r = 0; r < 4; ++r)
        scores[((size_t)(b * 128) + wm + i * 16 + l4 * 4 + r) * 4096 + nb + wn + j * 16 + l15] =
            acc[i][j][r];
}

// ---------------------------------------------------------------------------
// K5: per-(b,s) softmax stats over N=4096: m = max, linv = 1/sum(exp(v-m))
// ---------------------------------------------------------------------------
__global__ __launch_bounds__(256) void k5_stats(
    const float* __restrict__ scores, float* __restrict__ mbuf,
    float* __restrict__ lbuf)
{
  const int s = blockIdx.x, b = blockIdx.y, tid = threadIdx.x;
  if (s >= 110) {
    if (tid == 0) { mbuf[b * 128 + s] = 0.f; lbuf[b * 128 + s] = 0.f; }
    return;
  }
  const float* row = scores + ((size_t)(b * 128) + s) * 4096;
  float4 v[4];
  float m = -3.4e38f;
  #pragma unroll
  for (int j = 0; j < 4; ++j) {
    v[j] = *(const float4*)(row + (tid + 256 * j) * 4);
    m = fmaxf(m, fmaxf(fmaxf(v[j].x, v[j].y), fmaxf(v[j].z, v[j].w)));
  }
  #pragma unroll
  for (int off = 32; off > 0; off >>= 1) m = fmaxf(m, __shfl_down(m, off));
  __shared__ float red[8];
  if ((tid & 63) == 0) red[tid >> 6] = m;
  __syncthreads();
  float mm = fmaxf(fmaxf(red[0], red[1]), fmaxf(red[2], red[3]));
  float sum = 0.f;
  #pragma unroll
  for (int j = 0; j < 4; ++j)
    sum += __expf(v[j].x - mm) + __expf(v[j].y - mm) +
           __expf(v[j].z - mm) + __expf(v[j].w - mm);
  #pragma unroll
  for (int off = 32; off > 0; off >>= 1) sum += __shfl_down(sum, off);
  if ((tid & 63) == 0) red[4 + (tid >> 6)] = sum;
  __syncthreads();
  if (tid == 0) {
    float S = red[4] + red[5] + red[6] + red[7];
    mbuf[b * 128 + s] = mm;
    lbuf[b * 128 + s] = 1.f / S;
  }
}

// ---------------------------------------------------------------------------
// K5E: Eb[b,n,s] = bf16(exp(scores[b,s,n] - m[b,s]))  (transpose + exp)
// ---------------------------------------------------------------------------
__global__ __launch_bounds__(256) void k5e_expT(
    const float* __restrict__ scores, const float* __restrict__ mbuf,
    unsigned short* __restrict__ Eb)
{
  const int nt = blockIdx.x, b = blockIdx.y, tid = threadIdx.x;
  __shared__ float L[128 * 68];
  __shared__ float sm[128];
  if (tid < 128) sm[tid] = mbuf[b * 128 + tid];
  #pragma unroll
  for (int j = 0; j < 8; ++j) {
    int flat = tid + 256 * j;
    int s = flat >> 4, n4 = (flat & 15) << 2;
    *(float4*)&L[s * 68 + n4] =
        *(const float4*)(scores + ((size_t)(b * 128) + s) * 4096 + nt * 64 + n4);
  }
  __syncthreads();
  int n = tid >> 2, sq = (tid & 3) * 32;
  unsigned ub[16];
  #pragma unroll
  for (int k = 0; k < 32; k += 2) {
    float e0 = __expf(L[(sq + k) * 68 + n] - sm[sq + k]);
    float e1 = __expf(L[(sq + k + 1) * 68 + n] - sm[sq + k + 1]);
    ub[k >> 1] = pack2(e0, e1);
  }
  uint4* dst = (uint4*)(Eb + ((size_t)(b * 4096) + nt * 64 + n) * 128 + sq);
  #pragma unroll
  for (int j = 0; j < 4; ++j)
    dst[j] = make_uint4(ub[4 * j], ub[4 * j + 1], ub[4 * j + 2], ub[4 * j + 3]);
}

// ---------------------------------------------------------------------------
// K6: out[b,o,n] = sum_s (V[b,o,s]*linv[b,s]) * Eb[b,n,s] + x[b,o,n]
// ---------------------------------------------------------------------------
__global__ __launch_bounds__(256) void k6_out(
    const unsigned short* __restrict__ Eb, const float* __restrict__ V,
    const float* __restrict__ lbuf, const float* __restrict__ x,
    float* __restrict__ out)
{
  const int tid = threadIdx.x;
  const int nb = blockIdx.x * 128;
  const int mb = blockIdx.y * 128;
  const int b = blockIdx.z;
  const int lane = tid & 63, wv = tid >> 6;
  const int wm = (wv & 1) * 64, wn = (wv >> 1) * 64;
  const int l15 = lane & 15, l4 = lane >> 4;
  __shared__ unsigned short Ah[128 * 72];
  __shared__ unsigned short Bt[128 * 72];
  __shared__ float sl[128];
  if (tid < 128) sl[tid] = lbuf[b * 128 + tid];

  f32x4 acc[4][4];
  #pragma unroll
  for (int i = 0; i < 4; ++i)
    #pragma unroll
    for (int j = 0; j < 4; ++j) acc[i][j] = f32x4{0.f, 0.f, 0.f, 0.f};

  for (int kc = 0; kc < 128; kc += 64) {
    __syncthreads();
    #pragma unroll
    for (int j = 0; j < 8; ++j) {
      int flat = tid + 256 * j;
      int row = flat >> 4, s4 = (flat & 15) << 2;
      float4 v = *(const float4*)(V + ((size_t)(b * 512) + mb + row) * 128 + kc + s4);
      v.x *= sl[kc + s4]; v.y *= sl[kc + s4 + 1];
      v.z *= sl[kc + s4 + 2]; v.w *= sl[kc + s4 + 3];
      uint2 u; u.x = pack2(v.x, v.y); u.y = pack2(v.z, v.w);
      *(uint2*)&Ah[row * 72 + s4] = u;
    }
    #pragma unroll
    for (int j = 0; j < 4; ++j) {
      int flat = tid + 256 * j;
      int n = flat >> 3, s8 = (flat & 7) << 3;
      *(uint4*)&Bt[n * 72 + s8] =
          *(const uint4*)(Eb + ((size_t)(b * 4096) + nb + n) * 128 + kc + s8);
    }
    __syncthreads();
    #pragma unroll
    for (int kb = 0; kb < 64; kb += 32) {
      bf16x8 af[4], bfr[4];
      #pragma unroll
      for (int i = 0; i < 4; ++i)
        af[i] = *(const bf16x8*)&Ah[(wm + i * 16 + l15) * 72 + kb + l4 * 8];
      #pragma unroll
      for (int j = 0; j < 4; ++j)
        bfr[j] = *(const bf16x8*)&Bt[(wn + j * 16 + l15) * 72 + kb + l4 * 8];
      #pragma unroll
      for (int i = 0; i < 4; ++i)
        #pragma unroll
        for (int j = 0; j < 4; ++j)
          acc[i][j] = __builtin_amdgcn_mfma_f32_16x16x32_bf16(af[i], bfr[j], acc[i][j], 0, 0, 0);
    }
  }
  #pragma unroll
  for (int i = 0; i < 4; ++i)
    #pragma unroll
    for (int j = 0; j < 4; ++j)
      #pragma unroll
      for (int r = 0; r < 4; ++r) {
        int o = mb + wm + i * 16 + l4 * 4 + r;
        size_t idx = ((size_t)(b * 512) + o) * 4096 + nb + wn + j * 16 + l15;
        out[idx] = acc[i][j][r] + x[idx];
      }
}

// ---------------------------------------------------------------------------
extern "C" void kernel_launch(void* const* d_in, const int* in_sizes, int n_in,
                              void* d_out, int out_size, void* d_ws, size_t ws_size,
                              hipStream_t stream)
{
  (void)in_sizes; (void)n_in; (void)out_size; (void)ws_size;
  const float* x       = (const float*)d_in[0];
  const float* y       = (const float*)d_in[1];
  const float* w_phi   = (const float*)d_in[2];
  const float* w_theta = (const float*)d_in[3];
  const float* w_g     = (const float*)d_in[4];
  const float* w_mask  = (const float*)d_in[5];
  float* out = (float*)d_out;

  // Workspace: 130,039,808 B total (same as previous passing round).
  // Region A (67108864): yT, later overwritten by xT (after k1f).
  // Region B (54525952): Rbuf (18.9MB) -> scores (33.5MB, after k2f) | Eb | V.
  // Region C (8405?~8.4MB): Pt, Pg, Kth, Ktl, mbuf, lbuf.
  char* ws = (char*)d_ws;
  unsigned short* yT = (unsigned short*)ws;
  unsigned short* xT = yT;                                    // alias: after k1f
  char* B0 = ws + 67108864;
  unsigned short* Rbuf = (unsigned short*)B0;                 // 18874368 B
  float* scores = (float*)B0;                                 // 33554432 B (after k2f)
  unsigned short* Eb = (unsigned short*)(B0 + 33554432);      // 16777216 B
  float* V = (float*)(B0 + 50331648);                         // 4194304 B
  char* C0 = B0 + 54525952;
  float* Pt = (float*)C0;                                     // 2097152
  float* Pg = (float*)(C0 + 2097152);                         // 2097152
  unsigned short* Kth = (unsigned short*)(C0 + 4194304);      // 2097152
  unsigned short* Ktl = (unsigned short*)(C0 + 6291456);      // 2097152
  float* mbuf = (float*)(C0 + 8388608);                       // 8192
  float* lbuf = (float*)(C0 + 8396800);                       // 8192

  p0_transpose<<<dim3(64, 8, 16), 256, 0, stream>>>(y, yT);
  k1f_conv_pool<<<dim3(4, 32, 16), 256, 0, stream>>>(yT, w_theta, w_g, Rbuf);
  k2_pool_final<<<dim3(128, 16), 256, 0, stream>>>(Rbuf, Pt, Pg);
  k3_kmat<<<dim3(8, 16), 256, 0, stream>>>(Pt, w_phi, Kth, Ktl);
  k3_vmat<<<dim3(8, 16), 256, 0, stream>>>(Pg, w_mask, V);
  p0_transpose<<<dim3(64, 8, 16), 256, 0, stream>>>(x, xT);   // after k1f (alias)
  k4_scores<<<dim3(32, 16), 256, 0, stream>>>(xT, Kth, Ktl, scores); // after k2f (alias)
  k5_stats<<<dim3(128, 16), 256, 0, stream>>>(scores, mbuf, lbuf);
  k5e_expT<<<dim3(64, 16), 256, 0, stream>>>(scores, mbuf, Eb);
  k6_out<<<dim3(32, 4, 16), 256, 0, stream>>>(Eb, V, lbuf, x, out);
}